// Round 1
// baseline (12768.106 us; speedup 1.0000x reference)
//
#include <hip/hip_runtime.h>
#include <hip/hip_bf16.h>

#define BATCH   16
#define CH      256
#define IMG     112
#define WSZ     7
#define NWSIDE  16
#define TOK     49
#define TOKP    52
#define NHEAD   4
#define DHEAD   64
#define HID     512
#define NWIN    (BATCH*NWSIDE*NWSIDE)   // 4096

// element strides
#define SA_ST   260      // fp32 rows, 1040B (16B aligned)
#define WP_ST   66       // fp32 weight panel
#define QK_ST   68       // fp32 q/k/v rows (272B, 16B aligned)
#define SS_ST   76       // fp32 score rows
#define SD_ST   260      // bf16 rows (520B; 8B-aligned at c%4==0)
#define HM_ST   512      // bf16 hidden rows

// byte offsets in the LDS pool
#define OFF_A   0
#define SZ_A    (TOKP*SA_ST*4)            // 54080
#define OFF_WP  (OFF_A + SZ_A)            // 54080
#define SZ_WP   (64*WP_ST*4)              // 16896
#define OFF_Q   (OFF_WP + SZ_WP)          // 70976
#define SZ_QKV  (TOK*QK_ST*4)             // 13328
#define OFF_K   (OFF_Q + SZ_QKV)          // 84304
#define OFF_V   (OFF_K + SZ_QKV)          // 97632
#define OFF_S   (OFF_V + SZ_QKV)          // 110960
#define SZ_S    (TOKP*SS_ST*4)            // 15808 -> end 126768
#define OFF_HM  OFF_Q                     // bf16 52*512*2=53248 <= 55792, ends 124224 < OFF_D
#define OFF_D   (OFF_S + SZ_S)            // 126768
#define SZ_D    (TOKP*SD_ST*2)            // 27040 -> 153808
#define OFF_MR  (OFF_D + SZ_D)            // 153808
#define SMEM_SZ (OFF_MR + 2*TOK*4)        // 154200 <= 163840

__device__ __forceinline__ float bfu(unsigned short u) {
    return __uint_as_float(((unsigned)u) << 16);
}

extern "C" __global__ __launch_bounds__(256, 1)
void swin_block(const float* __restrict__ x,
                const float* __restrict__ ln1_g, const float* __restrict__ ln1_b,
                const float* __restrict__ qkv_w, const float* __restrict__ qkv_b,
                const float* __restrict__ proj_w, const float* __restrict__ proj_b,
                const float* __restrict__ ln2_g, const float* __restrict__ ln2_b,
                const float* __restrict__ w1, const float* __restrict__ b1,
                const float* __restrict__ w2, const float* __restrict__ b2,
                float* __restrict__ y)
{
    __shared__ __align__(16) char smem[SMEM_SZ];
    float*          sA  = (float*)(smem + OFF_A);
    float*          sWP = (float*)(smem + OFF_WP);
    float*          sQ  = (float*)(smem + OFF_Q);
    float*          sK  = (float*)(smem + OFF_K);
    float*          sV  = (float*)(smem + OFF_V);
    float*          sS  = (float*)(smem + OFF_S);
    __hip_bfloat16* sD  = (__hip_bfloat16*)(smem + OFF_D);
    unsigned short* sDu = (unsigned short*)(smem + OFF_D);
    __hip_bfloat16* sHM = (__hip_bfloat16*)(smem + OFF_HM);
    unsigned short* sHMu= (unsigned short*)(smem + OFF_HM);
    float*          sM  = (float*)(smem + OFF_MR);
    float*          sR  = sM + TOK;

    const int tid  = threadIdx.x;
    const int wid  = tid >> 6;       // wave id 0..3
    const int lane = tid & 63;
    const int tq   = wid;            // token group for GEMM phases
    const int col  = lane;           // output column 0..63

    const int n  = blockIdx.x;
    const int b  = n >> 8;
    const int wh = (n >> 4) & 15;
    const int ww = n & 15;
    const int row0 = wh * WSZ, col0 = ww * WSZ;
    const size_t xbase = (size_t)b * CH * IMG * IMG;

    // ---- P0: load window into sA [t][c]; zero pad rows of sA, sD, sS ----
    for (int e = tid; e < TOK*CH; e += 256) {
        int j = e % 7; int rem = e / 7; int i = rem % 7; int c = rem / 7;
        sA[(i*7 + j)*SA_ST + c] = x[xbase + ((size_t)c*IMG + row0 + i)*IMG + col0 + j];
    }
    for (int e = tid; e < 3*CH; e += 256)
        sA[(TOK + (e >> 8))*SA_ST + (e & 255)] = 0.f;
    for (int e = tid; e < 3*CH; e += 256)
        sDu[(TOK + (e >> 8))*SD_ST + (e & 255)] = 0;
    for (int e = tid; e < 3*TOK; e += 256)
        sS[(TOK + e/TOK)*SS_ST + (e % TOK)] = 0.f;
    __syncthreads();

    // ---- P1: LN1 stats (wave per token), then normalize sA in place ----
    for (int t = wid; t < TOK; t += 4) {
        const float4 v = *(const float4*)&sA[t*SA_ST + lane*4];
        float s1 = v.x + v.y + v.z + v.w;
        float s2 = v.x*v.x + v.y*v.y + v.z*v.z + v.w*v.w;
        for (int off = 32; off > 0; off >>= 1) {
            s1 += __shfl_xor(s1, off);
            s2 += __shfl_xor(s2, off);
        }
        if (lane == 0) {
            float m = s1 * (1.f/256.f);
            float var = s2 * (1.f/256.f) - m*m;
            sM[t] = m; sR[t] = rsqrtf(var + 1e-5f);
        }
    }
    __syncthreads();
    for (int e = tid; e < TOK*CH; e += 256) {
        int t = e >> 8, c = e & 255;
        sA[t*SA_ST + c] = (sA[t*SA_ST + c] - sM[t]) * sR[t] * ln1_g[c] + ln1_b[c];
    }

    // ---- attention, head by head ----
    for (int h = 0; h < NHEAD; ++h) {
        // QKV projections for this head (64 cols each)
        for (int mtx = 0; mtx < 3; ++mtx) {
            const int obase = mtx*CH + h*DHEAD;
            float acc[13];
            {
                const float bias = qkv_b[obase + col];
                #pragma unroll
                for (int k = 0; k < 13; ++k) acc[k] = bias;
            }
            for (int c0 = 0; c0 < CH; c0 += 64) {
                __syncthreads();
                #pragma unroll
                for (int it = 0; it < 16; ++it) {
                    int idx = it*256 + tid;
                    sWP[(idx >> 6)*WP_ST + (idx & 63)] =
                        qkv_w[(size_t)(c0 + (idx >> 6))*(3*CH) + obase + (idx & 63)];
                }
                __syncthreads();
                for (int c4 = 0; c4 < 16; ++c4) {
                    const float w0t = sWP[(c4*4+0)*WP_ST + col];
                    const float w1t = sWP[(c4*4+1)*WP_ST + col];
                    const float w2t = sWP[(c4*4+2)*WP_ST + col];
                    const float w3t = sWP[(c4*4+3)*WP_ST + col];
                    #pragma unroll
                    for (int k = 0; k < 13; ++k) {
                        const float4 a4 = *(const float4*)&sA[(tq + 4*k)*SA_ST + c0 + c4*4];
                        acc[k] += a4.x*w0t + a4.y*w1t + a4.z*w2t + a4.w*w3t;
                    }
                }
            }
            float* dst = (mtx == 0) ? sQ : (mtx == 1) ? sK : sV;
            #pragma unroll
            for (int k = 0; k < 13; ++k) {
                const int t = tq + 4*k;
                if (t < TOK) dst[t*QK_ST + col] = acc[k];
            }
        }
        __syncthreads();

        // scores = Q K^T / 8
        for (int e = tid; e < TOK*TOK; e += 256) {
            const int t = e / TOK;
            const int s = e - t*TOK;
            const float* qr = &sQ[t*QK_ST];
            const float* kr = &sK[s*QK_ST];
            float acc = 0.f;
            #pragma unroll
            for (int d4 = 0; d4 < 16; ++d4) {
                const float4 qv = *(const float4*)(qr + d4*4);
                const float4 kv = *(const float4*)(kr + d4*4);
                acc += qv.x*kv.x + qv.y*kv.y + qv.z*kv.z + qv.w*kv.w;
            }
            sS[t*SS_ST + s] = acc * 0.125f;
        }
        __syncthreads();

        // softmax over s (wave per row)
        for (int t = wid; t < TOK; t += 4) {
            float v  = (lane < TOK) ? sS[t*SS_ST + lane] : -3.4e38f;
            float mx = v;
            for (int off = 32; off > 0; off >>= 1) mx = fmaxf(mx, __shfl_xor(mx, off));
            float ex = (lane < TOK) ? __expf(v - mx) : 0.f;
            float sm = ex;
            for (int off = 32; off > 0; off >>= 1) sm += __shfl_xor(sm, off);
            if (lane < TOK) sS[t*SS_ST + lane] = ex / sm;
        }
        __syncthreads();

        // O_h = attn @ V  -> sD[:, h*64: h*64+64] (bf16)
        #pragma unroll
        for (int k = 0; k < 13; ++k) {
            const int t = tq + 4*k;
            if (t < TOK) {
                float acc = 0.f;
                for (int s = 0; s < TOK; ++s)
                    acc += sS[t*SS_ST + s] * sV[s*QK_ST + col];
                sD[t*SD_ST + h*DHEAD + col] = __float2bfloat16(acc);
            }
        }
        __syncthreads();
    }

    // ---- P5: proj + residual (x reloaded) -> sA becomes win2 ----
    for (int cg = 0; cg < 4; ++cg) {
        float acc[13];
        {
            const float bias = proj_b[cg*64 + col];
            #pragma unroll
            for (int k = 0; k < 13; ++k) acc[k] = bias;
        }
        for (int c0 = 0; c0 < CH; c0 += 64) {
            __syncthreads();
            #pragma unroll
            for (int it = 0; it < 16; ++it) {
                int idx = it*256 + tid;
                sWP[(idx >> 6)*WP_ST + (idx & 63)] =
                    proj_w[(size_t)(c0 + (idx >> 6))*CH + cg*64 + (idx & 63)];
            }
            __syncthreads();
            for (int c4 = 0; c4 < 16; ++c4) {
                const float w0t = sWP[(c4*4+0)*WP_ST + col];
                const float w1t = sWP[(c4*4+1)*WP_ST + col];
                const float w2t = sWP[(c4*4+2)*WP_ST + col];
                const float w3t = sWP[(c4*4+3)*WP_ST + col];
                #pragma unroll
                for (int k = 0; k < 13; ++k) {
                    const ushort4 dv = *(const ushort4*)&sDu[(tq + 4*k)*SD_ST + c0 + c4*4];
                    acc[k] += bfu(dv.x)*w0t + bfu(dv.y)*w1t + bfu(dv.z)*w2t + bfu(dv.w)*w3t;
                }
            }
        }
        #pragma unroll
        for (int k = 0; k < 13; ++k) {
            const int t = tq + 4*k;
            if (t < TOK) {
                const int c = cg*64 + col;
                const int i = t / 7, j = t - 7*(t/7);
                const float xv = x[xbase + ((size_t)c*IMG + row0 + i)*IMG + col0 + j];
                sA[t*SA_ST + c] = xv + acc[k];
            }
        }
    }
    __syncthreads();

    // ---- P6: LN2 -> n2 (bf16) into sD ----
    for (int t = wid; t < TOK; t += 4) {
        const float4 v = *(const float4*)&sA[t*SA_ST + lane*4];
        float s1 = v.x + v.y + v.z + v.w;
        float s2 = v.x*v.x + v.y*v.y + v.z*v.z + v.w*v.w;
        for (int off = 32; off > 0; off >>= 1) {
            s1 += __shfl_xor(s1, off);
            s2 += __shfl_xor(s2, off);
        }
        if (lane == 0) {
            float m = s1 * (1.f/256.f);
            float var = s2 * (1.f/256.f) - m*m;
            sM[t] = m; sR[t] = rsqrtf(var + 1e-5f);
        }
    }
    __syncthreads();
    for (int e = tid; e < TOK*CH; e += 256) {
        int t = e >> 8, c = e & 255;
        sD[t*SD_ST + c] =
            __float2bfloat16((sA[t*SA_ST + c] - sM[t]) * sR[t] * ln2_g[c] + ln2_b[c]);
    }
    // zero sHM pad rows (region aliases dead Q/K/V/S buffers)
    for (int e = tid; e < 3*HID; e += 256)
        sHMu[(TOK + e/HID)*HM_ST + (e % HID)] = 0;

    // ---- P7: MLP1 + exact-erf GELU -> sHM (bf16) ----
    for (int cg = 0; cg < 8; ++cg) {
        float acc[13];
        {
            const float bias = b1[cg*64 + col];
            #pragma unroll
            for (int k = 0; k < 13; ++k) acc[k] = bias;
        }
        for (int c0 = 0; c0 < CH; c0 += 64) {
            __syncthreads();
            #pragma unroll
            for (int it = 0; it < 16; ++it) {
                int idx = it*256 + tid;
                sWP[(idx >> 6)*WP_ST + (idx & 63)] =
                    w1[(size_t)(c0 + (idx >> 6))*HID + cg*64 + (idx & 63)];
            }
            __syncthreads();
            for (int c4 = 0; c4 < 16; ++c4) {
                const float w0t = sWP[(c4*4+0)*WP_ST + col];
                const float w1t = sWP[(c4*4+1)*WP_ST + col];
                const float w2t = sWP[(c4*4+2)*WP_ST + col];
                const float w3t = sWP[(c4*4+3)*WP_ST + col];
                #pragma unroll
                for (int k = 0; k < 13; ++k) {
                    const ushort4 dv = *(const ushort4*)&sDu[(tq + 4*k)*SD_ST + c0 + c4*4];
                    acc[k] += bfu(dv.x)*w0t + bfu(dv.y)*w1t + bfu(dv.z)*w2t + bfu(dv.w)*w3t;
                }
            }
        }
        #pragma unroll
        for (int k = 0; k < 13; ++k) {
            const int t = tq + 4*k;
            if (t < TOK) {
                const float v = acc[k];
                const float g = 0.5f * v * (1.f + erff(v * 0.70710678118654752f));
                sHM[t*HM_ST + cg*64 + col] = __float2bfloat16(g);
            }
        }
    }

    // ---- P8: MLP2 + residual into sA ----
    for (int cg = 0; cg < 4; ++cg) {
        float acc[13];
        {
            const float bias = b2[cg*64 + col];
            #pragma unroll
            for (int k = 0; k < 13; ++k) acc[k] = bias;
        }
        for (int h0 = 0; h0 < HID; h0 += 64) {
            __syncthreads();
            #pragma unroll
            for (int it = 0; it < 16; ++it) {
                int idx = it*256 + tid;
                sWP[(idx >> 6)*WP_ST + (idx & 63)] =
                    w2[(size_t)(h0 + (idx >> 6))*CH + cg*64 + (idx & 63)];
            }
            __syncthreads();
            for (int c4 = 0; c4 < 16; ++c4) {
                const float w0t = sWP[(c4*4+0)*WP_ST + col];
                const float w1t = sWP[(c4*4+1)*WP_ST + col];
                const float w2t = sWP[(c4*4+2)*WP_ST + col];
                const float w3t = sWP[(c4*4+3)*WP_ST + col];
                #pragma unroll
                for (int k = 0; k < 13; ++k) {
                    const ushort4 hv = *(const ushort4*)&sHMu[(tq + 4*k)*HM_ST + h0 + c4*4];
                    acc[k] += bfu(hv.x)*w0t + bfu(hv.y)*w1t + bfu(hv.z)*w2t + bfu(hv.w)*w3t;
                }
            }
        }
        #pragma unroll
        for (int k = 0; k < 13; ++k) {
            const int t = tq + 4*k;
            if (t < TOK) sA[t*SA_ST + cg*64 + col] += acc[k];
        }
    }
    __syncthreads();

    // ---- P9: window-reverse store ----
    for (int e = tid; e < TOK*CH; e += 256) {
        int j = e % 7; int rem = e / 7; int i = rem % 7; int c = rem / 7;
        y[xbase + ((size_t)c*IMG + row0 + i)*IMG + col0 + j] = sA[(i*7 + j)*SA_ST + c];
    }
}

extern "C" void kernel_launch(void* const* d_in, const int* in_sizes, int n_in,
                              void* d_out, int out_size, void* d_ws, size_t ws_size,
                              hipStream_t stream) {
    const float* x      = (const float*)d_in[0];
    const float* ln1_g  = (const float*)d_in[1];
    const float* ln1_b  = (const float*)d_in[2];
    const float* qkv_w  = (const float*)d_in[3];
    const float* qkv_b  = (const float*)d_in[4];
    const float* proj_w = (const float*)d_in[5];
    const float* proj_b = (const float*)d_in[6];
    const float* ln2_g  = (const float*)d_in[7];
    const float* ln2_b  = (const float*)d_in[8];
    const float* w1     = (const float*)d_in[9];
    const float* b1     = (const float*)d_in[10];
    const float* w2     = (const float*)d_in[11];
    const float* b2     = (const float*)d_in[12];

    hipLaunchKernelGGL(swin_block, dim3(NWIN), dim3(256), 0, stream,
                       x, ln1_g, ln1_b, qkv_w, qkv_b, proj_w, proj_b,
                       ln2_g, ln2_b, w1, b1, w2, b2, (float*)d_out);
}

// Round 2
// 1365.270 us; speedup vs baseline: 9.3521x; 9.3521x over previous
//
#include <hip/hip_runtime.h>
#include <hip/hip_bf16.h>

typedef __bf16 bf16x8 __attribute__((ext_vector_type(8)));
typedef float  f32x4  __attribute__((ext_vector_type(4)));
typedef unsigned short u16x8 __attribute__((ext_vector_type(8)));

#define CH    256
#define IMG   112
#define WSZ   7
#define TOK   49
#define NWIN  4096
#define HID   512

#define SX_ST 260          // f32 row stride for sX / sW staging

// ---- LDS arena (byte offsets), time-multiplexed ----
// [0..50960)      sX (raw x, f32)  -> V frags (32KB)      -> sW win2 (f32)
// [51200..83968)  n1F frags        -> P bufs (4x7168)     -> n2F frags
// [83968..116736) Q frags          -> HM (mlp hidden) frags
// [116736..149504) K frags         -> OF (attn out) frags
#define OFF_V    0
#define OFF_AF   51200
#define OFF_P    51200
#define PSZ      7168
#define OFF_Q    83968
#define OFF_HM   83968
#define OFF_K    116736
#define OFF_OF   116736
#define OFF_MR   149504     // sM[64], sR[64]
#define OFF_PRM  150016     // sG1,sB1,sG2,sB2 (each 256 f32)
#define SMEM_SZ  154112

// ---- d_ws layout: bf16 B-fragment blocks, 1KB each, consecutive ----
// qkv: blocks 0..383 (nt*8+kt), proj: 384..511, w1: 512..767, w2: 768..1023 (nt*16+kt)
#define WS_PROJ_BLK 384
#define WS_W1_BLK   512
#define WS_W2_BLK   768

__device__ __forceinline__ unsigned short f2bf(float f) {
    __bf16 h = (__bf16)f;
    return __builtin_bit_cast(unsigned short, h);
}

__device__ __forceinline__ f32x4 mfma16(bf16x8 a, bf16x8 b, f32x4 c) {
    return __builtin_amdgcn_mfma_f32_16x16x32_bf16(a, b, c, 0, 0, 0);
}

// element byte-offset in fragment-block layout over [t][c], 8 k-tiles per row-tile
__device__ __forceinline__ int frOff(int base, int t, int c) {
    return base + (((t >> 4) * 8 + (c >> 5)) << 10)
                + (((((c >> 3) & 3) << 4) | (t & 15)) << 4)
                + ((c & 7) << 1);
}
// element byte-offset in fragment-block layout over [c][t] (V^T), 2 t-tiles per row-tile
__device__ __forceinline__ int frOffT(int base, int c, int t) {
    return base + ((((c >> 4) << 1) + (t >> 5)) << 10)
                + (((((t >> 3) & 3) << 4) | (c & 15)) << 4)
                + ((t & 7) << 1);
}

// ---------------- prepack: fp32 weights -> bf16 B-fragment blocks in d_ws ----------------
extern "C" __global__ __launch_bounds__(64)
void prepack(const float* __restrict__ qkv_w, const float* __restrict__ proj_w,
             const float* __restrict__ w1, const float* __restrict__ w2,
             char* __restrict__ ws)
{
    const int blk = blockIdx.x, l = threadIdx.x;
    const float* W; int nt, kt, ncols;
    if (blk < WS_PROJ_BLK)      { W = qkv_w;  int i = blk;               nt = i >> 3; kt = i & 7;  ncols = 768; }
    else if (blk < WS_W1_BLK)   { W = proj_w; int i = blk - WS_PROJ_BLK; nt = i >> 3; kt = i & 7;  ncols = 256; }
    else if (blk < WS_W2_BLK)   { W = w1;     int i = blk - WS_W1_BLK;   nt = i >> 3; kt = i & 7;  ncols = 512; }
    else                        { W = w2;     int i = blk - WS_W2_BLK;   nt = i >> 4; kt = i & 15; ncols = 256; }
    const int n  = nt * 16 + (l & 15);
    const int k0 = kt * 32 + (l >> 4) * 8;
    u16x8 o;
    #pragma unroll
    for (int j = 0; j < 8; ++j) o[j] = f2bf(W[(size_t)(k0 + j) * ncols + n]);
    *(u16x8*)(ws + (size_t)blk * 1024 + l * 16) = o;
}

// ---------------- main fused block ----------------
extern "C" __global__ __launch_bounds__(256, 1)
void swin_block(const float* __restrict__ x,
                const float* __restrict__ ln1_g, const float* __restrict__ ln1_b,
                const float* __restrict__ qkv_b,
                const float* __restrict__ proj_b,
                const float* __restrict__ ln2_g, const float* __restrict__ ln2_b,
                const float* __restrict__ b1, const float* __restrict__ b2,
                const char* __restrict__ ws,
                float* __restrict__ y)
{
    __shared__ __align__(16) char smem[SMEM_SZ];
    float* sX = (float*)(smem + 0);          // also sW later
    float* sM = (float*)(smem + OFF_MR);
    float* sR = sM + 64;
    float* sG1 = (float*)(smem + OFF_PRM);
    float* sB1 = sG1 + 256;
    float* sG2 = sB1 + 256;
    float* sB2 = sG2 + 256;

    const int tid  = threadIdx.x;
    const int wid  = tid >> 6;
    const int lane = tid & 63;
    const int sub  = lane >> 4;
    const int l15  = lane & 15;

    const int n  = blockIdx.x;
    const int b  = n >> 8;
    const int wh = (n >> 4) & 15;
    const int ww = n & 15;
    const int row0 = wh * WSZ, col0 = ww * WSZ;
    const size_t xbase = (size_t)b * CH * IMG * IMG;

    const f32x4 z4 = {0.f, 0.f, 0.f, 0.f};

    // ---- P0: stage x -> sX; load LN params ----
    for (int e = tid; e < TOK * CH; e += 256) {
        int j = e % 7; int rem = e / 7; int i = rem % 7; int c = rem / 7;
        sX[(i * 7 + j) * SX_ST + c] = x[xbase + ((size_t)c * IMG + row0 + i) * IMG + col0 + j];
    }
    sG1[tid] = ln1_g[tid]; sB1[tid] = ln1_b[tid];
    sG2[tid] = ln2_g[tid]; sB2[tid] = ln2_b[tid];
    __syncthreads();   // 1

    // ---- P1: LN1 stats ----
    for (int t = wid; t < TOK; t += 4) {
        const float4 v = *(const float4*)&sX[t * SX_ST + lane * 4];
        float s1 = v.x + v.y + v.z + v.w;
        float s2 = v.x * v.x + v.y * v.y + v.z * v.z + v.w * v.w;
        #pragma unroll
        for (int off = 32; off > 0; off >>= 1) {
            s1 += __shfl_xor(s1, off);
            s2 += __shfl_xor(s2, off);
        }
        if (lane == 0) {
            float m = s1 * (1.f / 256.f);
            float var = s2 * (1.f / 256.f) - m * m;
            sM[t] = m; sR[t] = rsqrtf(var + 1e-5f);
        }
    }
    __syncthreads();   // 2

    // ---- P2: normalize -> n1F fragment blocks (t-major tasks); zero pad rows ----
    for (int e = tid; e < 2048; e += 256) {
        int t = e & 63, cb = e >> 6;
        char* dst = smem + OFF_AF + (((t >> 4) * 8 + (cb >> 2)) << 10)
                  + (((((cb & 3) << 4) | (t & 15))) << 4);
        if (t < TOK) {
            const float* xr = sX + t * SX_ST + cb * 8;
            float4 xa = *(const float4*)xr;
            float4 xb = *(const float4*)(xr + 4);
            float m = sM[t], rs = sR[t];
            int c = cb * 8;
            u16x8 o;
            o[0] = f2bf((xa.x - m) * rs * sG1[c + 0] + sB1[c + 0]);
            o[1] = f2bf((xa.y - m) * rs * sG1[c + 1] + sB1[c + 1]);
            o[2] = f2bf((xa.z - m) * rs * sG1[c + 2] + sB1[c + 2]);
            o[3] = f2bf((xa.w - m) * rs * sG1[c + 3] + sB1[c + 3]);
            o[4] = f2bf((xb.x - m) * rs * sG1[c + 4] + sB1[c + 4]);
            o[5] = f2bf((xb.y - m) * rs * sG1[c + 5] + sB1[c + 5]);
            o[6] = f2bf((xb.z - m) * rs * sG1[c + 6] + sB1[c + 6]);
            o[7] = f2bf((xb.w - m) * rs * sG1[c + 7] + sB1[c + 7]);
            *(u16x8*)dst = o;
        } else {
            u16x8 z = {0, 0, 0, 0, 0, 0, 0, 0};
            *(u16x8*)dst = z;
        }
    }
    __syncthreads();   // 3

    // ---- P3: QKV GEMM (M=64, N=768, K=256); wave w owns n-tiles w*12..w*12+11 ----
    {
        bf16x8 aF[4][8];
        #pragma unroll
        for (int mt = 0; mt < 4; ++mt)
            #pragma unroll
            for (int kt = 0; kt < 8; ++kt)
                aF[mt][kt] = *(const bf16x8*)(smem + OFF_AF + ((mt * 8 + kt) << 10) + lane * 16);

        for (int i = 0; i < 12; ++i) {
            const int ntg = wid * 12 + i;
            bf16x8 bF[8];
            #pragma unroll
            for (int kt = 0; kt < 8; ++kt)
                bF[kt] = *(const bf16x8*)(ws + (size_t)((ntg * 8 + kt) << 10) + lane * 16);
            f32x4 acc[4] = {z4, z4, z4, z4};
            #pragma unroll
            for (int kt = 0; kt < 8; ++kt)
                #pragma unroll
                for (int mt = 0; mt < 4; ++mt)
                    acc[mt] = mfma16(aF[mt][kt], bF[kt], acc[mt]);

            const float bias = qkv_b[ntg * 16 + l15];
            const int m3 = ntg >> 4;              // 0=Q 1=K 2=V
            const int c = (ntg & 15) * 16 + l15;  // col within matrix
            if (m3 == 2) {
                #pragma unroll
                for (int mt = 0; mt < 4; ++mt)
                    #pragma unroll
                    for (int r = 0; r < 4; ++r) {
                        int t = mt * 16 + sub * 4 + r;
                        *(unsigned short*)(smem + frOffT(OFF_V, c, t)) = f2bf(acc[mt][r] + bias);
                    }
            } else {
                const int base = m3 ? OFF_K : OFF_Q;
                #pragma unroll
                for (int mt = 0; mt < 4; ++mt)
                    #pragma unroll
                    for (int r = 0; r < 4; ++r) {
                        int t = mt * 16 + sub * 4 + r;
                        *(unsigned short*)(smem + frOff(base, t, c)) = f2bf(acc[mt][r] + bias);
                    }
            }
        }
    }
    __syncthreads();   // 4

    // ---- P4: attention, wave h = head h ----
    {
        const int h = wid;
        bf16x8 qf[4][2], kf[4][2];
        #pragma unroll
        for (int mt = 0; mt < 4; ++mt)
            #pragma unroll
            for (int k2 = 0; k2 < 2; ++k2) {
                qf[mt][k2] = *(const bf16x8*)(smem + OFF_Q + ((mt * 8 + h * 2 + k2) << 10) + lane * 16);
                kf[mt][k2] = *(const bf16x8*)(smem + OFF_K + ((mt * 8 + h * 2 + k2) << 10) + lane * 16);
            }
        f32x4 sc[4][4];
        #pragma unroll
        for (int mt = 0; mt < 4; ++mt)
            #pragma unroll
            for (int nt = 0; nt < 4; ++nt) sc[mt][nt] = z4;
        #pragma unroll
        for (int k2 = 0; k2 < 2; ++k2)
            #pragma unroll
            for (int mt = 0; mt < 4; ++mt)
                #pragma unroll
                for (int nt = 0; nt < 4; ++nt)
                    sc[mt][nt] = mfma16(qf[mt][k2], kf[nt][k2], sc[mt][nt]);

        // softmax over cols (s), rows t = mt*16+sub*4+r, cols s = nt*16+l15
        const int pbase = OFF_P + h * PSZ;
        #pragma unroll
        for (int mt = 0; mt < 4; ++mt) {
            #pragma unroll
            for (int r = 0; r < 4; ++r) {
                const int t = mt * 16 + sub * 4 + r;
                float v0 = sc[mt][0][r] * 0.125f;
                float v1 = sc[mt][1][r] * 0.125f;
                float v2 = sc[mt][2][r] * 0.125f;
                float v3 = (l15 == 0) ? sc[mt][3][r] * 0.125f : -1e30f;
                float mx = fmaxf(fmaxf(v0, v1), fmaxf(v2, v3));
                mx = fmaxf(mx, __shfl_xor(mx, 1));
                mx = fmaxf(mx, __shfl_xor(mx, 2));
                mx = fmaxf(mx, __shfl_xor(mx, 4));
                mx = fmaxf(mx, __shfl_xor(mx, 8));
                float e0 = __expf(v0 - mx), e1 = __expf(v1 - mx);
                float e2 = __expf(v2 - mx), e3 = __expf(v3 - mx);
                float s = e0 + e1 + e2 + e3;
                s += __shfl_xor(s, 1);
                s += __shfl_xor(s, 2);
                s += __shfl_xor(s, 4);
                s += __shfl_xor(s, 8);
                float inv = 1.f / s;
                if (t < TOK) {
                    unsigned short* pr = (unsigned short*)(smem + pbase + t * 144);
                    pr[l15]      = f2bf(e0 * inv);
                    pr[16 + l15] = f2bf(e1 * inv);
                    pr[32 + l15] = f2bf(e2 * inv);
                    pr[48 + l15] = f2bf(e3 * inv);
                }
            }
        }

        // PV: O_h = P @ V_h
        bf16x8 pf[4][2], vf[4][2];
        #pragma unroll
        for (int mt = 0; mt < 4; ++mt)
            #pragma unroll
            for (int k2 = 0; k2 < 2; ++k2) {
                int row = mt * 16 + l15; row = row > 48 ? 48 : row;
                pf[mt][k2] = *(const bf16x8*)(smem + pbase + row * 144 + ((k2 * 32 + sub * 8) << 1));
                vf[mt][k2] = *(const bf16x8*)(smem + OFF_V + ((((h * 4 + mt) << 1) + k2) << 10) + lane * 16);
            }
        f32x4 oc[4][4];
        #pragma unroll
        for (int mt = 0; mt < 4; ++mt)
            #pragma unroll
            for (int nt = 0; nt < 4; ++nt) oc[mt][nt] = z4;
        #pragma unroll
        for (int k2 = 0; k2 < 2; ++k2)
            #pragma unroll
            for (int mt = 0; mt < 4; ++mt)
                #pragma unroll
                for (int nt = 0; nt < 4; ++nt)
                    oc[mt][nt] = mfma16(pf[mt][k2], vf[nt][k2], oc[mt][nt]);
        #pragma unroll
        for (int mt = 0; mt < 4; ++mt)
            #pragma unroll
            for (int nt = 0; nt < 4; ++nt)
                #pragma unroll
                for (int r = 0; r < 4; ++r) {
                    int t = mt * 16 + sub * 4 + r;
                    int c = h * 64 + nt * 16 + l15;
                    *(unsigned short*)(smem + frOff(OFF_OF, t, c)) = f2bf(oc[mt][nt][r]);
                }
    }
    __syncthreads();   // 5 (V/P reads done; OF ready)

    // ---- P5: restage x -> sW (same region as sX) ----
    float* sW = sX;
    for (int e = tid; e < TOK * CH; e += 256) {
        int j = e % 7; int rem = e / 7; int i = rem % 7; int c = rem / 7;
        sW[(i * 7 + j) * SX_ST + c] = x[xbase + ((size_t)c * IMG + row0 + i) * IMG + col0 + j];
    }
    __syncthreads();   // 6

    // ---- P6: proj + residual; win2 = x + O@proj_w + b -> sW (RMW) ----
    {
        bf16x8 aF[4][8];
        #pragma unroll
        for (int mt = 0; mt < 4; ++mt)
            #pragma unroll
            for (int kt = 0; kt < 8; ++kt)
                aF[mt][kt] = *(const bf16x8*)(smem + OFF_OF + ((mt * 8 + kt) << 10) + lane * 16);
        #pragma unroll
        for (int i = 0; i < 4; ++i) {
            const int ntg = wid * 4 + i;
            bf16x8 bF[8];
            #pragma unroll
            for (int kt = 0; kt < 8; ++kt)
                bF[kt] = *(const bf16x8*)(ws + (size_t)(((WS_PROJ_BLK + ntg * 8 + kt)) << 10) + lane * 16);
            f32x4 acc[4] = {z4, z4, z4, z4};
            #pragma unroll
            for (int kt = 0; kt < 8; ++kt)
                #pragma unroll
                for (int mt = 0; mt < 4; ++mt)
                    acc[mt] = mfma16(aF[mt][kt], bF[kt], acc[mt]);
            const int c = ntg * 16 + l15;
            const float bias = proj_b[c];
            #pragma unroll
            for (int mt = 0; mt < 4; ++mt)
                #pragma unroll
                for (int r = 0; r < 4; ++r) {
                    int t = mt * 16 + sub * 4 + r;
                    if (t < TOK) sW[t * SX_ST + c] += acc[mt][r] + bias;
                }
        }
    }
    __syncthreads();   // 7

    // ---- P7: LN2 stats ----
    for (int t = wid; t < TOK; t += 4) {
        const float4 v = *(const float4*)&sW[t * SX_ST + lane * 4];
        float s1 = v.x + v.y + v.z + v.w;
        float s2 = v.x * v.x + v.y * v.y + v.z * v.z + v.w * v.w;
        #pragma unroll
        for (int off = 32; off > 0; off >>= 1) {
            s1 += __shfl_xor(s1, off);
            s2 += __shfl_xor(s2, off);
        }
        if (lane == 0) {
            float m = s1 * (1.f / 256.f);
            float var = s2 * (1.f / 256.f) - m * m;
            sM[t] = m; sR[t] = rsqrtf(var + 1e-5f);
        }
    }
    __syncthreads();   // 8

    // ---- P8: LN2 normalize -> n2F fragment blocks ----
    for (int e = tid; e < 2048; e += 256) {
        int t = e & 63, cb = e >> 6;
        char* dst = smem + OFF_AF + (((t >> 4) * 8 + (cb >> 2)) << 10)
                  + (((((cb & 3) << 4) | (t & 15))) << 4);
        if (t < TOK) {
            const float* xr = sW + t * SX_ST + cb * 8;
            float4 xa = *(const float4*)xr;
            float4 xb = *(const float4*)(xr + 4);
            float m = sM[t], rs = sR[t];
            int c = cb * 8;
            u16x8 o;
            o[0] = f2bf((xa.x - m) * rs * sG2[c + 0] + sB2[c + 0]);
            o[1] = f2bf((xa.y - m) * rs * sG2[c + 1] + sB2[c + 1]);
            o[2] = f2bf((xa.z - m) * rs * sG2[c + 2] + sB2[c + 2]);
            o[3] = f2bf((xa.w - m) * rs * sG2[c + 3] + sB2[c + 3]);
            o[4] = f2bf((xb.x - m) * rs * sG2[c + 4] + sB2[c + 4]);
            o[5] = f2bf((xb.y - m) * rs * sG2[c + 5] + sB2[c + 5]);
            o[6] = f2bf((xb.z - m) * rs * sG2[c + 6] + sB2[c + 6]);
            o[7] = f2bf((xb.w - m) * rs * sG2[c + 7] + sB2[c + 7]);
            *(u16x8*)dst = o;
        } else {
            u16x8 z = {0, 0, 0, 0, 0, 0, 0, 0};
            *(u16x8*)dst = z;
        }
    }
    __syncthreads();   // 9

    // ---- P9: MLP in two k-halves; hmid ping-pongs in HM (Q region) ----
    {
        f32x4 a2[4][4];
        #pragma unroll
        for (int i = 0; i < 4; ++i)
            #pragma unroll
            for (int mt = 0; mt < 4; ++mt) a2[i][mt] = z4;

        for (int half = 0; half < 2; ++half) {
            // MLP1: n2 @ w1[:, half*256 : half*256+256] + b1, GELU -> HM
            {
                bf16x8 nf[4][8];
                #pragma unroll
                for (int mt = 0; mt < 4; ++mt)
                    #pragma unroll
                    for (int kt = 0; kt < 8; ++kt)
                        nf[mt][kt] = *(const bf16x8*)(smem + OFF_AF + ((mt * 8 + kt) << 10) + lane * 16);
                #pragma unroll
                for (int i = 0; i < 4; ++i) {
                    const int ntg = wid * 4 + i;            // local n-tile 0..15
                    bf16x8 bF[8];
                    #pragma unroll
                    for (int kt = 0; kt < 8; ++kt)
                        bF[kt] = *(const bf16x8*)(ws + (size_t)(((WS_W1_BLK + (half * 16 + ntg) * 8 + kt)) << 10) + lane * 16);
                    f32x4 acc[4] = {z4, z4, z4, z4};
                    #pragma unroll
                    for (int kt = 0; kt < 8; ++kt)
                        #pragma unroll
                        for (int mt = 0; mt < 4; ++mt)
                            acc[mt] = mfma16(nf[mt][kt], bF[kt], acc[mt]);
                    const int chm = ntg * 16 + l15;         // 0..255 within half
                    const float bias = b1[half * 256 + chm];
                    #pragma unroll
                    for (int mt = 0; mt < 4; ++mt)
                        #pragma unroll
                        for (int r = 0; r < 4; ++r) {
                            int t = mt * 16 + sub * 4 + r;
                            if (t < TOK) {
                                float v = acc[mt][r] + bias;
                                // tanh-form GELU (abs err < 1e-3, below bf16 quantum here)
                                float u = v * (1.5957691216f + 0.07135481627f * v * v);
                                float g = v / (1.f + __expf(-u));
                                *(unsigned short*)(smem + frOff(OFF_HM, t, chm)) = f2bf(g);
                            }
                        }
                }
            }
            __syncthreads();   // HM ready

            // MLP2 partial: accumulate HM @ w2[half*256 : half*256+256, :]
            {
                bf16x8 hf[4][8];
                #pragma unroll
                for (int mt = 0; mt < 4; ++mt)
                    #pragma unroll
                    for (int kt = 0; kt < 8; ++kt)
                        hf[mt][kt] = *(const bf16x8*)(smem + OFF_HM + ((mt * 8 + kt) << 10) + lane * 16);
                #pragma unroll
                for (int i = 0; i < 4; ++i) {
                    const int ntg = wid * 4 + i;
                    bf16x8 bF[8];
                    #pragma unroll
                    for (int kt = 0; kt < 8; ++kt)
                        bF[kt] = *(const bf16x8*)(ws + (size_t)(((WS_W2_BLK + ntg * 16 + half * 8 + kt)) << 10) + lane * 16);
                    #pragma unroll
                    for (int kt = 0; kt < 8; ++kt)
                        #pragma unroll
                        for (int mt = 0; mt < 4; ++mt)
                            a2[i][mt] = mfma16(hf[mt][kt], bF[kt], a2[i][mt]);
                }
            }
            __syncthreads();   // HM reads done (safe to overwrite next half)
        }

        // epilogue: win2 += mlp2 + b2
        #pragma unroll
        for (int i = 0; i < 4; ++i) {
            const int c = (wid * 4 + i) * 16 + l15;
            const float bias = b2[c];
            #pragma unroll
            for (int mt = 0; mt < 4; ++mt)
                #pragma unroll
                for (int r = 0; r < 4; ++r) {
                    int t = mt * 16 + sub * 4 + r;
                    if (t < TOK) sW[t * SX_ST + c] += a2[i][mt][r] + bias;
                }
        }
    }
    __syncthreads();   // final

    // ---- P10: window-reverse store ----
    for (int e = tid; e < TOK * CH; e += 256) {
        int j = e % 7; int rem = e / 7; int i = rem % 7; int c = rem / 7;
        y[xbase + ((size_t)c * IMG + row0 + i) * IMG + col0 + j] = sW[(i * 7 + j) * SX_ST + c];
    }
}

extern "C" void kernel_launch(void* const* d_in, const int* in_sizes, int n_in,
                              void* d_out, int out_size, void* d_ws, size_t ws_size,
                              hipStream_t stream) {
    const float* x      = (const float*)d_in[0];
    const float* ln1_g  = (const float*)d_in[1];
    const float* ln1_b  = (const float*)d_in[2];
    const float* qkv_w  = (const float*)d_in[3];
    const float* qkv_b  = (const float*)d_in[4];
    const float* proj_w = (const float*)d_in[5];
    const float* proj_b = (const float*)d_in[6];
    const float* ln2_g  = (const float*)d_in[7];
    const float* ln2_b  = (const float*)d_in[8];
    const float* w1     = (const float*)d_in[9];
    const float* b1     = (const float*)d_in[10];
    const float* w2     = (const float*)d_in[11];
    const float* b2     = (const float*)d_in[12];

    hipLaunchKernelGGL(prepack, dim3(1024), dim3(64), 0, stream,
                       qkv_w, proj_w, w1, w2, (char*)d_ws);
    hipLaunchKernelGGL(swin_block, dim3(NWIN), dim3(256), 0, stream,
                       x, ln1_g, ln1_b, qkv_b, proj_b, ln2_g, ln2_b, b1, b2,
                       (const char*)d_ws, (float*)d_out);
}

// Round 3
// 993.637 us; speedup vs baseline: 12.8499x; 1.3740x over previous
//
#include <hip/hip_runtime.h>
#include <hip/hip_bf16.h>

typedef __bf16 bf16x8 __attribute__((ext_vector_type(8)));
typedef float  f32x4  __attribute__((ext_vector_type(4)));
typedef unsigned short u16x8 __attribute__((ext_vector_type(8)));

#define CH    256
#define IMG   112
#define WSZ   7
#define TOK   49
#define NWIN  4096
#define HID   512

#define SX_ST 260          // f32 row stride for sX / sW staging

// ---- LDS arena (byte offsets), time-multiplexed ----
#define OFF_V    0
#define OFF_AF   51200
#define OFF_P    51200
#define PSZ      7168
#define OFF_Q    83968
#define OFF_HM   83968
#define OFF_K    116736
#define OFF_OF   116736
#define OFF_MR   149504     // sM[64], sR[64]
#define OFF_PRM  150016     // sG1,sB1,sG2,sB2 (each 256 f32)
#define SMEM_SZ  154112

// ---- d_ws layout: bf16 B-fragment blocks, 1KB each ----
#define WS_PROJ_BLK 384
#define WS_W1_BLK   512
#define WS_W2_BLK   768

__device__ __forceinline__ unsigned short f2bf(float f) {
    __bf16 h = (__bf16)f;
    return __builtin_bit_cast(unsigned short, h);
}

__device__ __forceinline__ f32x4 mfma16(bf16x8 a, bf16x8 b, f32x4 c) {
    return __builtin_amdgcn_mfma_f32_16x16x32_bf16(a, b, c, 0, 0, 0);
}

__device__ __forceinline__ int frOff(int base, int t, int c) {
    return base + (((t >> 4) * 8 + (c >> 5)) << 10)
                + (((((c >> 3) & 3) << 4) | (t & 15)) << 4)
                + ((c & 7) << 1);
}
__device__ __forceinline__ int frOffT(int base, int c, int t) {
    return base + ((((c >> 4) << 1) + (t >> 5)) << 10)
                + (((((t >> 3) & 3) << 4) | (c & 15)) << 4)
                + ((t & 7) << 1);
}

// ---------------- prepack: fp32 weights -> bf16 B-fragment blocks in d_ws ----------------
extern "C" __global__ __launch_bounds__(64)
void prepack(const float* __restrict__ qkv_w, const float* __restrict__ proj_w,
             const float* __restrict__ w1, const float* __restrict__ w2,
             char* __restrict__ ws)
{
    const int blk = blockIdx.x, l = threadIdx.x;
    const float* W; int nt, kt, ncols;
    if (blk < WS_PROJ_BLK)      { W = qkv_w;  int i = blk;               nt = i >> 3; kt = i & 7;  ncols = 768; }
    else if (blk < WS_W1_BLK)   { W = proj_w; int i = blk - WS_PROJ_BLK; nt = i >> 3; kt = i & 7;  ncols = 256; }
    else if (blk < WS_W2_BLK)   { W = w1;     int i = blk - WS_W1_BLK;   nt = i >> 3; kt = i & 7;  ncols = 512; }
    else                        { W = w2;     int i = blk - WS_W2_BLK;   nt = i >> 4; kt = i & 15; ncols = 256; }
    const int n  = nt * 16 + (l & 15);
    const int k0 = kt * 32 + (l >> 4) * 8;
    u16x8 o;
    #pragma unroll
    for (int j = 0; j < 8; ++j) o[j] = f2bf(W[(size_t)(k0 + j) * ncols + n]);
    *(u16x8*)(ws + (size_t)blk * 1024 + l * 16) = o;
}

// ---------------- main fused block: 8 waves ----------------
extern "C" __global__ __launch_bounds__(512, 1)
void swin_block(const float* __restrict__ x,
                const float* __restrict__ ln1_g, const float* __restrict__ ln1_b,
                const float* __restrict__ qkv_b,
                const float* __restrict__ proj_b,
                const float* __restrict__ ln2_g, const float* __restrict__ ln2_b,
                const float* __restrict__ b1, const float* __restrict__ b2,
                const char* __restrict__ ws,
                float* __restrict__ y)
{
    __shared__ __align__(16) char smem[SMEM_SZ];
    float* sX = (float*)(smem + 0);          // also sW later
    float* sM = (float*)(smem + OFF_MR);
    float* sR = sM + 64;
    float* sG1 = (float*)(smem + OFF_PRM);
    float* sB1 = sG1 + 256;
    float* sG2 = sB1 + 256;
    float* sB2 = sG2 + 256;

    const int tid  = threadIdx.x;
    const int wid  = tid >> 6;       // 0..7
    const int lane = tid & 63;
    const int sub  = lane >> 4;
    const int l15  = lane & 15;
    const int mg   = wid >> 2;       // m-group 0..1 (row-tiles mg*2, mg*2+1)
    const int ng   = wid & 3;        // n-group 0..3

    const int n  = blockIdx.x;
    const int b  = n >> 8;
    const int wh = (n >> 4) & 15;
    const int ww = n & 15;
    const int row0 = wh * WSZ, col0 = ww * WSZ;
    const size_t xbase = (size_t)b * CH * IMG * IMG;

    const f32x4 z4 = {0.f, 0.f, 0.f, 0.f};

    // ---- P0: stage x -> sX; load LN params ----
    for (int e = tid; e < TOK * CH; e += 512) {
        int j = e % 7; int rem = e / 7; int i = rem % 7; int c = rem / 7;
        sX[(i * 7 + j) * SX_ST + c] = x[xbase + ((size_t)c * IMG + row0 + i) * IMG + col0 + j];
    }
    {
        int t2 = tid & 255;
        if (tid < 256) { sG1[t2] = ln1_g[t2]; sB1[t2] = ln1_b[t2]; }
        else           { sG2[t2] = ln2_g[t2]; sB2[t2] = ln2_b[t2]; }
    }
    __syncthreads();   // 1

    // ---- P1: LN1 stats ----
    for (int t = wid; t < TOK; t += 8) {
        const float4 v = *(const float4*)&sX[t * SX_ST + lane * 4];
        float s1 = v.x + v.y + v.z + v.w;
        float s2 = v.x * v.x + v.y * v.y + v.z * v.z + v.w * v.w;
        #pragma unroll
        for (int off = 32; off > 0; off >>= 1) {
            s1 += __shfl_xor(s1, off);
            s2 += __shfl_xor(s2, off);
        }
        if (lane == 0) {
            float m = s1 * (1.f / 256.f);
            float var = s2 * (1.f / 256.f) - m * m;
            sM[t] = m; sR[t] = rsqrtf(var + 1e-5f);
        }
    }
    __syncthreads();   // 2

    // ---- P2: normalize -> n1F fragment blocks; zero pad rows ----
    for (int e = tid; e < 2048; e += 512) {
        int t = e & 63, cb = e >> 6;
        char* dst = smem + OFF_AF + (((t >> 4) * 8 + (cb >> 2)) << 10)
                  + (((((cb & 3) << 4) | (t & 15))) << 4);
        if (t < TOK) {
            const float* xr = sX + t * SX_ST + cb * 8;
            float4 xa = *(const float4*)xr;
            float4 xb = *(const float4*)(xr + 4);
            float m = sM[t], rs = sR[t];
            int c = cb * 8;
            u16x8 o;
            o[0] = f2bf((xa.x - m) * rs * sG1[c + 0] + sB1[c + 0]);
            o[1] = f2bf((xa.y - m) * rs * sG1[c + 1] + sB1[c + 1]);
            o[2] = f2bf((xa.z - m) * rs * sG1[c + 2] + sB1[c + 2]);
            o[3] = f2bf((xa.w - m) * rs * sG1[c + 3] + sB1[c + 3]);
            o[4] = f2bf((xb.x - m) * rs * sG1[c + 4] + sB1[c + 4]);
            o[5] = f2bf((xb.y - m) * rs * sG1[c + 5] + sB1[c + 5]);
            o[6] = f2bf((xb.z - m) * rs * sG1[c + 6] + sB1[c + 6]);
            o[7] = f2bf((xb.w - m) * rs * sG1[c + 7] + sB1[c + 7]);
            *(u16x8*)dst = o;
        } else {
            u16x8 z = {0, 0, 0, 0, 0, 0, 0, 0};
            *(u16x8*)dst = z;
        }
    }
    __syncthreads();   // 3

    // ---- P3: QKV GEMM (M=64,N=768,K=256); wave (mg,ng): mt=mg*2+m, ntg=ng*12+i ----
    {
        bf16x8 aF[2][8];
        #pragma unroll
        for (int m = 0; m < 2; ++m)
            #pragma unroll
            for (int kt = 0; kt < 8; ++kt)
                aF[m][kt] = *(const bf16x8*)(smem + OFF_AF + (((mg * 2 + m) * 8 + kt) << 10) + lane * 16);

        auto qkv_epi = [&](int ntg, const f32x4 (&acc)[2]) {
            const float bias = qkv_b[ntg * 16 + l15];
            const int m3 = ntg >> 4;              // 0=Q 1=K 2=V
            const int c = (ntg & 15) * 16 + l15;
            if (m3 == 2) {
                #pragma unroll
                for (int m = 0; m < 2; ++m)
                    #pragma unroll
                    for (int r = 0; r < 4; ++r) {
                        int t = (mg * 2 + m) * 16 + sub * 4 + r;
                        *(unsigned short*)(smem + frOffT(OFF_V, c, t)) = f2bf(acc[m][r] + bias);
                    }
            } else if (m3 == 1) {
                #pragma unroll
                for (int m = 0; m < 2; ++m)
                    #pragma unroll
                    for (int r = 0; r < 4; ++r) {
                        int t = (mg * 2 + m) * 16 + sub * 4 + r;
                        *(unsigned short*)(smem + frOff(OFF_K, t, c)) = f2bf(acc[m][r] + bias);
                    }
            } else {
                #pragma unroll
                for (int m = 0; m < 2; ++m)
                    #pragma unroll
                    for (int r = 0; r < 4; ++r) {
                        int t = (mg * 2 + m) * 16 + sub * 4 + r;
                        *(unsigned short*)(smem + frOff(OFF_Q, t, c)) = f2bf((acc[m][r] + bias) * 0.125f);
                    }
            }
        };

        bf16x8 bA[8], bB[8];
        #pragma unroll
        for (int kt = 0; kt < 8; ++kt)
            bA[kt] = *(const bf16x8*)(ws + (size_t)(((ng * 12) * 8 + kt) << 10) + lane * 16);

        for (int i = 0; i < 12; i += 2) {
            const int n0 = ng * 12 + i;
            #pragma unroll
            for (int kt = 0; kt < 8; ++kt)
                bB[kt] = *(const bf16x8*)(ws + (size_t)(((n0 + 1) * 8 + kt) << 10) + lane * 16);
            {
                f32x4 acc[2] = {z4, z4};
                #pragma unroll
                for (int kt = 0; kt < 8; ++kt)
                    #pragma unroll
                    for (int m = 0; m < 2; ++m)
                        acc[m] = mfma16(aF[m][kt], bA[kt], acc[m]);
                qkv_epi(n0, acc);
            }
            if (i + 2 < 12) {
                #pragma unroll
                for (int kt = 0; kt < 8; ++kt)
                    bA[kt] = *(const bf16x8*)(ws + (size_t)(((n0 + 2) * 8 + kt) << 10) + lane * 16);
            }
            {
                f32x4 acc[2] = {z4, z4};
                #pragma unroll
                for (int kt = 0; kt < 8; ++kt)
                    #pragma unroll
                    for (int m = 0; m < 2; ++m)
                        acc[m] = mfma16(aF[m][kt], bB[kt], acc[m]);
                qkv_epi(n0 + 1, acc);
            }
        }
    }
    __syncthreads();   // 4

    // ---- P4: attention; wave = (head h = wid>>1, m-half ah = wid&1) ----
    {
        const int h  = wid >> 1;
        const int ah = wid & 1;
        bf16x8 qf[2][2], kf[4][2];
        #pragma unroll
        for (int m = 0; m < 2; ++m)
            #pragma unroll
            for (int k2 = 0; k2 < 2; ++k2)
                qf[m][k2] = *(const bf16x8*)(smem + OFF_Q + (((ah * 2 + m) * 8 + h * 2 + k2) << 10) + lane * 16);
        #pragma unroll
        for (int nt = 0; nt < 4; ++nt)
            #pragma unroll
            for (int k2 = 0; k2 < 2; ++k2)
                kf[nt][k2] = *(const bf16x8*)(smem + OFF_K + ((nt * 8 + h * 2 + k2) << 10) + lane * 16);

        f32x4 sc[2][4];
        #pragma unroll
        for (int m = 0; m < 2; ++m)
            #pragma unroll
            for (int nt = 0; nt < 4; ++nt) sc[m][nt] = z4;
        #pragma unroll
        for (int k2 = 0; k2 < 2; ++k2)
            #pragma unroll
            for (int m = 0; m < 2; ++m)
                #pragma unroll
                for (int nt = 0; nt < 4; ++nt)
                    sc[m][nt] = mfma16(qf[m][k2], kf[nt][k2], sc[m][nt]);

        const int pbase = OFF_P + h * PSZ;
        #pragma unroll
        for (int m = 0; m < 2; ++m) {
            #pragma unroll
            for (int r = 0; r < 4; ++r) {
                const int t = (ah * 2 + m) * 16 + sub * 4 + r;
                float v0 = sc[m][0][r];
                float v1 = sc[m][1][r];
                float v2 = sc[m][2][r];
                float v3 = (l15 == 0) ? sc[m][3][r] : -1e30f;
                float mx = fmaxf(fmaxf(v0, v1), fmaxf(v2, v3));
                mx = fmaxf(mx, __shfl_xor(mx, 1));
                mx = fmaxf(mx, __shfl_xor(mx, 2));
                mx = fmaxf(mx, __shfl_xor(mx, 4));
                mx = fmaxf(mx, __shfl_xor(mx, 8));
                float e0 = __expf(v0 - mx), e1 = __expf(v1 - mx);
                float e2 = __expf(v2 - mx), e3 = __expf(v3 - mx);
                float s = e0 + e1 + e2 + e3;
                s += __shfl_xor(s, 1);
                s += __shfl_xor(s, 2);
                s += __shfl_xor(s, 4);
                s += __shfl_xor(s, 8);
                float inv = 1.f / s;
                if (t < TOK) {
                    unsigned short* pr = (unsigned short*)(smem + pbase + t * 144);
                    pr[l15]      = f2bf(e0 * inv);
                    pr[16 + l15] = f2bf(e1 * inv);
                    pr[32 + l15] = f2bf(e2 * inv);
                    pr[48 + l15] = f2bf(e3 * inv);
                }
            }
        }

        // PV: O_h rows of this m-half
        bf16x8 pf[2][2], vf[4][2];
        #pragma unroll
        for (int m = 0; m < 2; ++m)
            #pragma unroll
            for (int k2 = 0; k2 < 2; ++k2) {
                int row = (ah * 2 + m) * 16 + l15; row = row > 48 ? 48 : row;
                pf[m][k2] = *(const bf16x8*)(smem + pbase + row * 144 + ((k2 * 32 + sub * 8) << 1));
            }
        #pragma unroll
        for (int nt = 0; nt < 4; ++nt)
            #pragma unroll
            for (int k2 = 0; k2 < 2; ++k2)
                vf[nt][k2] = *(const bf16x8*)(smem + OFF_V + ((((h * 4 + nt) << 1) + k2) << 10) + lane * 16);

        f32x4 oc[2][4];
        #pragma unroll
        for (int m = 0; m < 2; ++m)
            #pragma unroll
            for (int nt = 0; nt < 4; ++nt) oc[m][nt] = z4;
        #pragma unroll
        for (int k2 = 0; k2 < 2; ++k2)
            #pragma unroll
            for (int m = 0; m < 2; ++m)
                #pragma unroll
                for (int nt = 0; nt < 4; ++nt)
                    oc[m][nt] = mfma16(pf[m][k2], vf[nt][k2], oc[m][nt]);
        #pragma unroll
        for (int m = 0; m < 2; ++m)
            #pragma unroll
            for (int nt = 0; nt < 4; ++nt)
                #pragma unroll
                for (int r = 0; r < 4; ++r) {
                    int t = (ah * 2 + m) * 16 + sub * 4 + r;
                    int c = h * 64 + nt * 16 + l15;
                    *(unsigned short*)(smem + frOff(OFF_OF, t, c)) = f2bf(oc[m][nt][r]);
                }
    }
    __syncthreads();   // 5

    // ---- P5: restage x -> sW ----
    float* sW = sX;
    for (int e = tid; e < TOK * CH; e += 512) {
        int j = e % 7; int rem = e / 7; int i = rem % 7; int c = rem / 7;
        sW[(i * 7 + j) * SX_ST + c] = x[xbase + ((size_t)c * IMG + row0 + i) * IMG + col0 + j];
    }
    __syncthreads();   // 6

    // ---- P6: proj + residual -> sW ----
    {
        bf16x8 aF[2][8];
        #pragma unroll
        for (int m = 0; m < 2; ++m)
            #pragma unroll
            for (int kt = 0; kt < 8; ++kt)
                aF[m][kt] = *(const bf16x8*)(smem + OFF_OF + (((mg * 2 + m) * 8 + kt) << 10) + lane * 16);

        auto proj_epi = [&](int ntg, const f32x4 (&acc)[2]) {
            const int c = ntg * 16 + l15;
            const float bias = proj_b[c];
            #pragma unroll
            for (int m = 0; m < 2; ++m)
                #pragma unroll
                for (int r = 0; r < 4; ++r) {
                    int t = (mg * 2 + m) * 16 + sub * 4 + r;
                    if (t < TOK) sW[t * SX_ST + c] += acc[m][r] + bias;
                }
        };

        bf16x8 bA[8], bB[8];
        #pragma unroll
        for (int kt = 0; kt < 8; ++kt)
            bA[kt] = *(const bf16x8*)(ws + (size_t)(((WS_PROJ_BLK + (ng * 4) * 8 + kt)) << 10) + lane * 16);
        for (int i = 0; i < 4; i += 2) {
            const int n0 = ng * 4 + i;
            #pragma unroll
            for (int kt = 0; kt < 8; ++kt)
                bB[kt] = *(const bf16x8*)(ws + (size_t)(((WS_PROJ_BLK + (n0 + 1) * 8 + kt)) << 10) + lane * 16);
            {
                f32x4 acc[2] = {z4, z4};
                #pragma unroll
                for (int kt = 0; kt < 8; ++kt)
                    #pragma unroll
                    for (int m = 0; m < 2; ++m)
                        acc[m] = mfma16(aF[m][kt], bA[kt], acc[m]);
                proj_epi(n0, acc);
            }
            if (i + 2 < 4) {
                #pragma unroll
                for (int kt = 0; kt < 8; ++kt)
                    bA[kt] = *(const bf16x8*)(ws + (size_t)(((WS_PROJ_BLK + (n0 + 2) * 8 + kt)) << 10) + lane * 16);
            }
            {
                f32x4 acc[2] = {z4, z4};
                #pragma unroll
                for (int kt = 0; kt < 8; ++kt)
                    #pragma unroll
                    for (int m = 0; m < 2; ++m)
                        acc[m] = mfma16(aF[m][kt], bB[kt], acc[m]);
                proj_epi(n0 + 1, acc);
            }
        }
    }
    __syncthreads();   // 7

    // ---- P7: LN2 stats ----
    for (int t = wid; t < TOK; t += 8) {
        const float4 v = *(const float4*)&sW[t * SX_ST + lane * 4];
        float s1 = v.x + v.y + v.z + v.w;
        float s2 = v.x * v.x + v.y * v.y + v.z * v.z + v.w * v.w;
        #pragma unroll
        for (int off = 32; off > 0; off >>= 1) {
            s1 += __shfl_xor(s1, off);
            s2 += __shfl_xor(s2, off);
        }
        if (lane == 0) {
            float m = s1 * (1.f / 256.f);
            float var = s2 * (1.f / 256.f) - m * m;
            sM[t] = m; sR[t] = rsqrtf(var + 1e-5f);
        }
    }
    __syncthreads();   // 8

    // ---- P8: LN2 normalize -> n2F ----
    for (int e = tid; e < 2048; e += 512) {
        int t = e & 63, cb = e >> 6;
        char* dst = smem + OFF_AF + (((t >> 4) * 8 + (cb >> 2)) << 10)
                  + (((((cb & 3) << 4) | (t & 15))) << 4);
        if (t < TOK) {
            const float* xr = sW + t * SX_ST + cb * 8;
            float4 xa = *(const float4*)xr;
            float4 xb = *(const float4*)(xr + 4);
            float m = sM[t], rs = sR[t];
            int c = cb * 8;
            u16x8 o;
            o[0] = f2bf((xa.x - m) * rs * sG2[c + 0] + sB2[c + 0]);
            o[1] = f2bf((xa.y - m) * rs * sG2[c + 1] + sB2[c + 1]);
            o[2] = f2bf((xa.z - m) * rs * sG2[c + 2] + sB2[c + 2]);
            o[3] = f2bf((xa.w - m) * rs * sG2[c + 3] + sB2[c + 3]);
            o[4] = f2bf((xb.x - m) * rs * sG2[c + 4] + sB2[c + 4]);
            o[5] = f2bf((xb.y - m) * rs * sG2[c + 5] + sB2[c + 5]);
            o[6] = f2bf((xb.z - m) * rs * sG2[c + 6] + sB2[c + 6]);
            o[7] = f2bf((xb.w - m) * rs * sG2[c + 7] + sB2[c + 7]);
            *(u16x8*)dst = o;
        } else {
            u16x8 z = {0, 0, 0, 0, 0, 0, 0, 0};
            *(u16x8*)dst = z;
        }
    }
    __syncthreads();   // 9

    // ---- P9: MLP in two K-halves; hmid ping-pongs in HM ----
    {
        f32x4 a20[2] = {z4, z4}, a21[2] = {z4, z4}, a22[2] = {z4, z4}, a23[2] = {z4, z4};

        for (int half = 0; half < 2; ++half) {
            // MLP1: n2 @ w1[:, half*256 +: 256] + b1, GELU -> HM
            {
                bf16x8 nf[2][8];
                #pragma unroll
                for (int m = 0; m < 2; ++m)
                    #pragma unroll
                    for (int kt = 0; kt < 8; ++kt)
                        nf[m][kt] = *(const bf16x8*)(smem + OFF_AF + (((mg * 2 + m) * 8 + kt) << 10) + lane * 16);

                auto mlp1_epi = [&](int ntg, const f32x4 (&acc)[2]) {
                    const int chm = ntg * 16 + l15;
                    const float bias = b1[half * 256 + chm];
                    #pragma unroll
                    for (int m = 0; m < 2; ++m)
                        #pragma unroll
                        for (int r = 0; r < 4; ++r) {
                            int t = (mg * 2 + m) * 16 + sub * 4 + r;
                            if (t < TOK) {
                                float v = acc[m][r] + bias;
                                float u = v * (1.5957691216f + 0.07135481627f * v * v);
                                float g = v / (1.f + __expf(-u));
                                *(unsigned short*)(smem + frOff(OFF_HM, t, chm)) = f2bf(g);
                            }
                        }
                };

                bf16x8 bA[8], bB[8];
                #pragma unroll
                for (int kt = 0; kt < 8; ++kt)
                    bA[kt] = *(const bf16x8*)(ws + (size_t)(((WS_W1_BLK + (half * 16 + ng * 4) * 8 + kt)) << 10) + lane * 16);
                for (int i = 0; i < 4; i += 2) {
                    const int n0 = ng * 4 + i;
                    #pragma unroll
                    for (int kt = 0; kt < 8; ++kt)
                        bB[kt] = *(const bf16x8*)(ws + (size_t)(((WS_W1_BLK + (half * 16 + n0 + 1) * 8 + kt)) << 10) + lane * 16);
                    {
                        f32x4 acc[2] = {z4, z4};
                        #pragma unroll
                        for (int kt = 0; kt < 8; ++kt)
                            #pragma unroll
                            for (int m = 0; m < 2; ++m)
                                acc[m] = mfma16(nf[m][kt], bA[kt], acc[m]);
                        mlp1_epi(n0, acc);
                    }
                    if (i + 2 < 4) {
                        #pragma unroll
                        for (int kt = 0; kt < 8; ++kt)
                            bA[kt] = *(const bf16x8*)(ws + (size_t)(((WS_W1_BLK + (half * 16 + n0 + 2) * 8 + kt)) << 10) + lane * 16);
                    }
                    {
                        f32x4 acc[2] = {z4, z4};
                        #pragma unroll
                        for (int kt = 0; kt < 8; ++kt)
                            #pragma unroll
                            for (int m = 0; m < 2; ++m)
                                acc[m] = mfma16(nf[m][kt], bB[kt], acc[m]);
                        mlp1_epi(n0 + 1, acc);
                    }
                }
            }
            __syncthreads();   // HM ready

            // MLP2 partial: accumulate HM @ w2[half*256 +: 256, :]
            {
                bf16x8 hf[2][8];
                #pragma unroll
                for (int m = 0; m < 2; ++m)
                    #pragma unroll
                    for (int kt = 0; kt < 8; ++kt)
                        hf[m][kt] = *(const bf16x8*)(smem + OFF_HM + (((mg * 2 + m) * 8 + kt) << 10) + lane * 16);

                bf16x8 bA[8], bB[8];
                #pragma unroll
                for (int kt = 0; kt < 8; ++kt)
                    bA[kt] = *(const bf16x8*)(ws + (size_t)(((WS_W2_BLK + (ng * 4 + 0) * 16 + half * 8 + kt)) << 10) + lane * 16);
                #pragma unroll
                for (int kt = 0; kt < 8; ++kt)
                    bB[kt] = *(const bf16x8*)(ws + (size_t)(((WS_W2_BLK + (ng * 4 + 1) * 16 + half * 8 + kt)) << 10) + lane * 16);
                #pragma unroll
                for (int kt = 0; kt < 8; ++kt)
                    #pragma unroll
                    for (int m = 0; m < 2; ++m)
                        a20[m] = mfma16(hf[m][kt], bA[kt], a20[m]);
                #pragma unroll
                for (int kt = 0; kt < 8; ++kt)
                    bA[kt] = *(const bf16x8*)(ws + (size_t)(((WS_W2_BLK + (ng * 4 + 2) * 16 + half * 8 + kt)) << 10) + lane * 16);
                #pragma unroll
                for (int kt = 0; kt < 8; ++kt)
                    #pragma unroll
                    for (int m = 0; m < 2; ++m)
                        a21[m] = mfma16(hf[m][kt], bB[kt], a21[m]);
                #pragma unroll
                for (int kt = 0; kt < 8; ++kt)
                    bB[kt] = *(const bf16x8*)(ws + (size_t)(((WS_W2_BLK + (ng * 4 + 3) * 16 + half * 8 + kt)) << 10) + lane * 16);
                #pragma unroll
                for (int kt = 0; kt < 8; ++kt)
                    #pragma unroll
                    for (int m = 0; m < 2; ++m)
                        a22[m] = mfma16(hf[m][kt], bA[kt], a22[m]);
                #pragma unroll
                for (int kt = 0; kt < 8; ++kt)
                    #pragma unroll
                    for (int m = 0; m < 2; ++m)
                        a23[m] = mfma16(hf[m][kt], bB[kt], a23[m]);
            }
            __syncthreads();   // HM reads done
        }

        // epilogue: win2 += mlp2 + b2
        auto mlp2_epi = [&](int i, const f32x4 (&acc)[2]) {
            const int c = (ng * 4 + i) * 16 + l15;
            const float bias = b2[c];
            #pragma unroll
            for (int m = 0; m < 2; ++m)
                #pragma unroll
                for (int r = 0; r < 4; ++r) {
                    int t = (mg * 2 + m) * 16 + sub * 4 + r;
                    if (t < TOK) sW[t * SX_ST + c] += acc[m][r] + bias;
                }
        };
        mlp2_epi(0, a20); mlp2_epi(1, a21); mlp2_epi(2, a22); mlp2_epi(3, a23);
    }
    __syncthreads();   // final

    // ---- P10: window-reverse store ----
    for (int e = tid; e < TOK * CH; e += 512) {
        int j = e % 7; int rem = e / 7; int i = rem % 7; int c = rem / 7;
        y[xbase + ((size_t)c * IMG + row0 + i) * IMG + col0 + j] = sW[(i * 7 + j) * SX_ST + c];
    }
}

extern "C" void kernel_launch(void* const* d_in, const int* in_sizes, int n_in,
                              void* d_out, int out_size, void* d_ws, size_t ws_size,
                              hipStream_t stream) {
    const float* x      = (const float*)d_in[0];
    const float* ln1_g  = (const float*)d_in[1];
    const float* ln1_b  = (const float*)d_in[2];
    const float* qkv_w  = (const float*)d_in[3];
    const float* qkv_b  = (const float*)d_in[4];
    const float* proj_w = (const float*)d_in[5];
    const float* proj_b = (const float*)d_in[6];
    const float* ln2_g  = (const float*)d_in[7];
    const float* ln2_b  = (const float*)d_in[8];
    const float* w1     = (const float*)d_in[9];
    const float* b1     = (const float*)d_in[10];
    const float* w2     = (const float*)d_in[11];
    const float* b2     = (const float*)d_in[12];

    hipLaunchKernelGGL(prepack, dim3(1024), dim3(64), 0, stream,
                       qkv_w, proj_w, w1, w2, (char*)d_ws);
    hipLaunchKernelGGL(swin_block, dim3(NWIN), dim3(512), 0, stream,
                       x, ln1_g, ln1_b, qkv_b, proj_b, ln2_g, ln2_b, b1, b2,
                       (const char*)d_ws, (float*)d_out);
}